// Round 8
// baseline (44.327 us; speedup 1.0000x reference)
//
#include <hip/hip_runtime.h>

#define NTHR 512
#define TB 32

typedef __attribute__((ext_vector_type(8))) short bf16x8;
typedef __attribute__((ext_vector_type(4))) float f32x4;
typedef float4 f4;
typedef unsigned short u16;

__device__ __forceinline__ u16 f2b(float x) {
  union { float f; unsigned u; } v; v.f = x;
  unsigned r = (v.u + 0x7fffu + ((v.u >> 16) & 1u)) >> 16;
  return (u16)r;
}
__device__ __forceinline__ float b2f(u16 u) {
  union { unsigned u; float f; } v; v.u = ((unsigned)u) << 16;
  return v.f;
}
__device__ __forceinline__ unsigned pack2(float a, float b) {
  return (unsigned)f2b(a) | ((unsigned)f2b(b) << 16);
}
__device__ __forceinline__ unsigned cvtpk(float lo, float hi) {
  unsigned r;
  asm("v_cvt_pk_bf16_f32 %0, %1, %2" : "=v"(r) : "v"(lo), "v"(hi));
  return r;
}
__device__ __forceinline__ float blo(unsigned u) {
  union { unsigned u; float f; } v; v.u = u << 16; return v.f;
}
__device__ __forceinline__ float bhi(unsigned u) {
  union { unsigned u; float f; } v; v.u = u & 0xffff0000u; return v.f;
}

// ---------------- prep: MFMA-fragment-ordered bf16 weights in ws ----------------
// BTf : frag_id = (a*10+kt)*9+p ; lane l, 8 k's: k' = kt*32+(l>>4)*8+j, col s=l&15
//       k' = q*18+r; k'>=306 or r==17 -> 0.
// UcTf: frag_id = (c*4+a)*8+kt;  k = kt*32+(l>>4)*8+j, col r = l&15.
// UOTf: frag_id = a*16+ht;       k = (l>>4)*8+j (k>=16 -> 0), col h = ht*16+(l&15).
extern "C" __global__ void hosvd_prep(const float* __restrict__ U,
                                      const float* __restrict__ T,
                                      const float* __restrict__ UO,
                                      unsigned* __restrict__ ws32) {
  int id = blockIdx.x * 256 + threadIdx.x;
  if (id < 92160) {                       // BTf: 23040 frags * 4 u32
    int j2 = id & 3, frag = id >> 2;
    int l = frag & 63, f2 = frag >> 6;    // f2 = (a*10+kt)*9+p
    int p = f2 % 9, akt = f2 / 9;
    int kt = akt % 10, a = akt / 10;
    int s = l & 15;
    float v[2];
    #pragma unroll
    for (int j = 0; j < 2; ++j) {
      int kp = kt * 32 + (l >> 4) * 8 + j2 * 2 + j;
      float x = 0.f;
      if (kp < 306) {
        int q = (unsigned)kp / 18u, r = kp - q * 18;
        if (r < 17) x = T[(((a * 9 + p) * 17 + q) * 17 + r) * 16 + s];
      }
      v[j] = x;
    }
    ws32[id] = pack2(v[0], v[1]);
  } else if (id < 108544) {               // UcTf: 4096 frags * 4 u32
    int rel = id - 92160;
    int j2 = rel & 3, frag = rel >> 2;
    int l = frag & 63, f2 = frag >> 6;
    int kt = f2 & 7, g = f2 >> 3;
    int a = g & 3, c = g >> 2;
    int rr = l & 15;
    int k = kt * 32 + (l >> 4) * 8 + j2 * 2;
    float v0 = U[((c * 4 + a) * 256 + k + 0) * 16 + rr];
    float v1 = U[((c * 4 + a) * 256 + k + 1) * 16 + rr];
    ws32[id] = pack2(v0, v1);
  } else if (id < 124928) {               // UOTf: 4096 frags * 4 u32
    int rel = id - 108544;
    int j2 = rel & 3, frag = rel >> 2;
    int l = frag & 63, f2 = frag >> 6;
    int ht = f2 & 15, a = f2 >> 4;
    int h = ht * 16 + (l & 15);
    int k = (l >> 4) * 8 + j2 * 2;
    float v0 = (k + 0 < 16) ? UO[(a * 16 + k + 0) * 256 + h] : 0.f;
    float v1 = (k + 1 < 16) ? UO[(a * 16 + k + 1) * 256 + h] : 0.f;
    ws32[id] = pack2(v0, v1);
  }
}

#define MFMA_B(A, B, C) __builtin_amdgcn_mfma_f32_16x16x32_bf16(A, B, C, 0, 0, 0)

// load one p-column (KTN frags) of BTf into a rotating register set
#define LOADP(DST, P, KTN)                                                   \
  do {                                                                       \
    _Pragma("unroll")                                                        \
    for (int kk = 0; kk < (KTN); ++kk)                                       \
      DST[kk] = *(const bf16x8*)&BTf[(size_t)((a * 10 + kt0 + kk) * 9 + (P)) * 512 + l * 8]; \
  } while (0)

// K-slice MFMAs for one p (both m-tiles) + immediate h0-weighted fold into gp
#define DOP(BSET, P, KTN)                                                    \
  do {                                                                       \
    f32x4 c0_ = {0.f, 0.f, 0.f, 0.f}, c1_ = {0.f, 0.f, 0.f, 0.f};            \
    _Pragma("unroll")                                                        \
    for (int kk = 0; kk < (KTN); ++kk) {                                     \
      c0_ = MFMA_B(Af0[kk], BSET[kk], c0_);                                  \
      c1_ = MFMA_B(Af1[kk], BSET[kk], c1_);                                  \
    }                                                                        \
    f4 tv0_ = *(const f4*)&s_tpt[(a * 9 + (P)) * 32 + 4 * q];                \
    f4 tv1_ = *(const f4*)&s_tpt[(a * 9 + (P)) * 32 + 16 + 4 * q];           \
    gp0[0] = fmaf(tv0_.x, c0_[0], gp0[0]);                                   \
    gp0[1] = fmaf(tv0_.y, c0_[1], gp0[1]);                                   \
    gp0[2] = fmaf(tv0_.z, c0_[2], gp0[2]);                                   \
    gp0[3] = fmaf(tv0_.w, c0_[3], gp0[3]);                                   \
    gp1[0] = fmaf(tv1_.x, c1_[0], gp1[0]);                                   \
    gp1[1] = fmaf(tv1_.y, c1_[1], gp1[1]);                                   \
    gp1[2] = fmaf(tv1_.z, c1_[2], gp1[2]);                                   \
    gp1[3] = fmaf(tv1_.w, c1_[3], gp1[3]);                                   \
  } while (0)

// full p-pipeline: 3 rotating B sets, loads run ~2.5 columns ahead
#define CORE_GEMM(KTN)                                                       \
  do {                                                                       \
    const u16* oa_ = &s_u[aL * 10496];                                       \
    bf16x8 Af0[KTN], Af1[KTN];                                               \
    _Pragma("unroll")                                                        \
    for (int kk = 0; kk < (KTN); ++kk) {                                     \
      Af0[kk] = *(const bf16x8*)&oa_[rl * 328 + (kt0 + kk) * 32 + 8 * q];    \
      Af1[kk] = *(const bf16x8*)&oa_[(16 + rl) * 328 + (kt0 + kk) * 32 + 8 * q]; \
    }                                                                        \
    bf16x8 Ba[KTN], Bb[KTN], Bc[KTN];                                        \
    LOADP(Ba, 0, KTN); LOADP(Bb, 1, KTN); LOADP(Bc, 2, KTN);                 \
    DOP(Ba, 0, KTN); LOADP(Ba, 3, KTN);                                      \
    DOP(Bb, 1, KTN); LOADP(Bb, 4, KTN);                                      \
    DOP(Bc, 2, KTN); LOADP(Bc, 5, KTN);                                      \
    DOP(Ba, 3, KTN); LOADP(Ba, 6, KTN);                                      \
    DOP(Bb, 4, KTN); LOADP(Bb, 7, KTN);                                      \
    DOP(Bc, 5, KTN); LOADP(Bc, 8, KTN);                                      \
    DOP(Ba, 6, KTN);                                                         \
    DOP(Bb, 7, KTN);                                                         \
    DOP(Bc, 8, KTN);                                                         \
  } while (0)

// ---------------- main fused kernel ----------------
// LDS (78848 B -> 2 blocks/CU):
//  s_u   [20992] u16: nh [32][520] (early) | O [aL][32][328] (k'=q*18+r)
//  s_ch  [32][164] u16: h[row][c*80 + a*20 + idx]; idx16=1.0, idx17=0 sentinels
//  s_tpt [36][32] f32: tp transposed [a*9+p][row]; p=8 row = 1.0 sentinel
//  s_g   [32][136] u16: [row][a*32 + s]; slots 16..31 zero (K-pad for phase E)
//  s_red [3264] f32: te [32][33] + Ut [1024] (early) | 3-slice k-split reduce
extern "C" __global__ __launch_bounds__(NTHR, 4)
void hosvd_main(const float* __restrict__ nh, const float* __restrict__ te,
                const float* __restrict__ bw, const float* __restrict__ Ut,
                const float* __restrict__ bt, const float* __restrict__ bO,
                const u16* __restrict__ BTf, const u16* __restrict__ UcTf,
                const u16* __restrict__ UOTf, float* __restrict__ out) {
  __shared__ __align__(16) u16   s_u[20992];
  __shared__ __align__(16) u16   s_ch[TB * 164];
  __shared__ __align__(16) float s_tpt[36 * 32];
  __shared__ __align__(16) u16   s_g[TB * 136];
  __shared__ __align__(16) float s_red[3264];

  const int t = threadIdx.x;
  const int ib0 = blockIdx.x * TB;
  const int w = t >> 6, l = t & 63;
  const int rl = l & 15, q = l >> 4;

  //---- sentinels ----
  {  // s_ch: h[16]=1.0, h[17]=0 for every (row, c, a)  (exactly 512 slots)
    const int row = t >> 4, cc = (t >> 3) & 1, aa = (t >> 1) & 3, sl = t & 1;
    s_ch[row * 164 + cc * 80 + aa * 20 + 16 + sl] = sl ? (u16)0 : (u16)0x3F80;
  }
  if (t < 128) {  // s_tpt p=8 row = 1.0
    const int aa = t >> 5, row = t & 31;
    s_tpt[(aa * 9 + 8) * 32 + row] = 1.0f;
  }

  //---- stage te -> s_red[0..1055], Ut -> s_red[1056..2079], nh -> s_u ----
  if (t < 256) {
    const int row = t >> 3, k4 = t & 7;
    f4 v = *(const f4*)&te[(size_t)(ib0 + row) * 32 + k4 * 4];
    float* d = &s_red[row * 33 + k4 * 4];
    d[0] = v.x; d[1] = v.y; d[2] = v.z; d[3] = v.w;
  } else {
    const int j = t - 256;                         // 256 f4 = 1024 floats of Ut
    *(f4*)&s_red[1056 + j * 4] = *(const f4*)&Ut[j * 4];
  }
  for (int lp = t; lp < 4096; lp += NTHR) {
    const int row = lp >> 7, rem = lp & 127;
    const int c = rem >> 6, k0 = (rem & 63) * 4;
    f4 v = *(const f4*)&nh[((size_t)(ib0 + row) * 2 + c) * 256 + k0];
    *(uint2*)&s_u[row * 520 + c * 256 + k0] =
        make_uint2(cvtpk(v.x, v.y), cvtpk(v.z, v.w));
  }
  __syncthreads();

  //---- Phase B: tp = te @ Ut + bt -> s_tpt (transposed, f32) ----
  {
    const int i = t >> 4, o = t & 15;
    const int off = o * 2;
    const int aa = off >> 3, p0 = off & 7;
    float acc0 = bt[off], acc1 = bt[off + 1];
    #pragma unroll
    for (int k = 0; k < 32; ++k) {
      float tv = s_red[i * 33 + k];
      float2 u = *(const float2*)&s_red[1056 + k * 32 + off];
      acc0 = fmaf(tv, u.x, acc0);
      acc1 = fmaf(tv, u.y, acc1);
    }
    s_tpt[(aa * 9 + p0) * 32 + i]     = acc0;
    s_tpt[(aa * 9 + p0 + 1) * 32 + i] = acc1;
  }

  //---- Phase C: ch = nh @ U + bw -> s_ch. Wave (c, a): both m, 2 MFMA/frag ----
  {
    const int c = w >> 2, a = w & 3;
    const u16* u0 = &UcTf[((size_t)((c * 4 + a) * 8) * 64 + l) * 8];
    bf16x8 C0 = *(const bf16x8*)(u0 + 0 * 512);
    bf16x8 C1 = *(const bf16x8*)(u0 + 1 * 512);
    bf16x8 C2 = *(const bf16x8*)(u0 + 2 * 512);
    bf16x8 C3 = *(const bf16x8*)(u0 + 3 * 512);
    bf16x8 C4 = *(const bf16x8*)(u0 + 4 * 512);
    bf16x8 C5 = *(const bf16x8*)(u0 + 5 * 512);
    bf16x8 C6 = *(const bf16x8*)(u0 + 6 * 512);
    bf16x8 C7 = *(const bf16x8*)(u0 + 7 * 512);
    f32x4 ac0 = {0.f, 0.f, 0.f, 0.f}, ac1 = {0.f, 0.f, 0.f, 0.f};
    #define PCKT(KT, CB)                                                          \
    {                                                                             \
      bf16x8 A0_ = *(const bf16x8*)&s_u[rl * 520 + c * 256 + KT * 32 + 8 * q];    \
      bf16x8 A1_ = *(const bf16x8*)&s_u[(16 + rl) * 520 + c * 256 + KT * 32 + 8 * q]; \
      ac0 = MFMA_B(A0_, CB, ac0);                                                 \
      ac1 = MFMA_B(A1_, CB, ac1);                                                 \
    }
    PCKT(0, C0) PCKT(1, C1) PCKT(2, C2) PCKT(3, C3)
    PCKT(4, C4) PCKT(5, C5) PCKT(6, C6) PCKT(7, C7)
    #undef PCKT
    const float bias = bw[(c * 4 + a) * 16 + rl];
    #pragma unroll
    for (int reg = 0; reg < 4; ++reg) {
      s_ch[(4 * q + reg) * 164 + c * 80 + a * 20 + rl]      = f2b(ac0[reg] + bias);
      s_ch[(16 + 4 * q + reg) * 164 + c * 80 + a * 20 + rl] = f2b(ac1[reg] + bias);
    }
  }
  __syncthreads();   // s_ch, s_tpt ready; nh reads done (s_u reusable)

  //---- Core: 2 a-pair iterations; wave = (aL, kq 4-way k-split), both m ----
  const int aL = w >> 2;
  const int kq = w & 3;
  const int kt0 = (kq <= 2) ? kq * 3 : 8;   // kt groups {0-2},{3-5},{6-7},{8-9}

  for (int it = 0; it < 2; ++it) {
    const int aB = it * 2;
    const int a = aB + aL;

    //-- O-build for BOTH aggregators of the pair: 1152 units (row, aLb, qv) --
    for (int lp = t; lp < 1152; lp += NTHR) {
      const int row = lp & 31, rest = lp >> 5;      // rest 0..35
      const int aLb = (rest >= 18) ? 1 : 0;
      const int qv = rest - aLb * 18;               // 0..17 (17: h1 sentinel=0)
      const int ab = aB + aLb;
      const float h1f = b2f(s_ch[row * 164 + ab * 20 + qv]);
      const u16* h2p = &s_ch[row * 164 + 80 + ab * 20];
      uint2 ha = *(const uint2*)&h2p[0];
      uint2 hb = *(const uint2*)&h2p[4];
      uint2 hc = *(const uint2*)&h2p[8];
      uint2 hd = *(const uint2*)&h2p[12];
      unsigned he = *(const unsigned*)&h2p[16];
      unsigned* op = (unsigned*)&s_u[aLb * 10496 + row * 328 + qv * 18];
      op[0] = cvtpk(h1f * blo(ha.x), h1f * bhi(ha.x));
      op[1] = cvtpk(h1f * blo(ha.y), h1f * bhi(ha.y));
      op[2] = cvtpk(h1f * blo(hb.x), h1f * bhi(hb.x));
      op[3] = cvtpk(h1f * blo(hb.y), h1f * bhi(hb.y));
      op[4] = cvtpk(h1f * blo(hc.x), h1f * bhi(hc.x));
      op[5] = cvtpk(h1f * blo(hc.y), h1f * bhi(hc.y));
      op[6] = cvtpk(h1f * blo(hd.x), h1f * bhi(hd.x));
      op[7] = cvtpk(h1f * blo(hd.y), h1f * bhi(hd.y));
      op[8] = cvtpk(h1f * blo(he),   h1f * bhi(he));
    }
    __syncthreads();

    //-- p-outer pipelined GEMM + immediate h0 fold --
    f32x4 gp0 = {0.f, 0.f, 0.f, 0.f}, gp1 = {0.f, 0.f, 0.f, 0.f};
    __builtin_amdgcn_s_setprio(1);
    if (kq < 2) { CORE_GEMM(3); } else { CORE_GEMM(2); }
    __builtin_amdgcn_s_setprio(0);

    if (kq) {
      #pragma unroll
      for (int reg = 0; reg < 4; ++reg) {
        s_red[((kq - 1) * 2 + aL) * 544 + (4 * q + reg) * 17 + rl]       = gp0[reg];
        s_red[((kq - 1) * 2 + aL) * 544 + 272 + (4 * q + reg) * 17 + rl] = gp1[reg];
      }
    }
    __syncthreads();

    if (kq == 0) {
      #pragma unroll
      for (int mm = 0; mm < 2; ++mm)
        #pragma unroll
        for (int reg = 0; reg < 4; ++reg) {
          const int idx = aL * 544 + mm * 272 + (4 * q + reg) * 17 + rl;
          float g = (mm ? gp1[reg] : gp0[reg]) +
                    s_red[idx] + s_red[1088 + idx] + s_red[2176 + idx];
          const int row = mm * 16 + 4 * q + reg;
          s_g[row * 136 + a * 32 + rl]      = f2b(g);
          s_g[row * 136 + a * 32 + 16 + rl] = 0;
        }
    }
  }
  __syncthreads();   // s_g ready for all waves

  //---- Phase E: out = g @ U_output + b_output. Wave e: ht {2e, 2e+1}, both m ----
  {
    const int e = w;
    #pragma unroll
    for (int a = 0; a < 4; ++a) {
      const u16* ub = &UOTf[((size_t)(a * 16 + e * 2) * 64 + l) * 8];
      bf16x8 E0 = *(const bf16x8*)(ub);
      bf16x8 E1 = *(const bf16x8*)(ub + 512);
      bf16x8 A0 = *(const bf16x8*)&s_g[rl * 136 + a * 32 + 8 * q];
      bf16x8 A1 = *(const bf16x8*)&s_g[(16 + rl) * 136 + a * 32 + 8 * q];
      const float b0 = bO[a * 256 + (e * 2 + 0) * 16 + rl];
      const float b1 = bO[a * 256 + (e * 2 + 1) * 16 + rl];
      f32x4 e00 = {b0, b0, b0, b0}, e01 = e00;
      f32x4 e10 = {b1, b1, b1, b1}, e11 = e10;
      e00 = MFMA_B(A0, E0, e00);
      e01 = MFMA_B(A1, E0, e01);
      e10 = MFMA_B(A0, E1, e10);
      e11 = MFMA_B(A1, E1, e11);
      #pragma unroll
      for (int reg = 0; reg < 4; ++reg) {
        const size_t r0 = (size_t)(ib0 + 4 * q + reg) * 1024 + a * 256;
        const size_t r1 = (size_t)(ib0 + 16 + 4 * q + reg) * 1024 + a * 256;
        out[r0 + (e * 2 + 0) * 16 + rl] = e00[reg];
        out[r1 + (e * 2 + 0) * 16 + rl] = e01[reg];
        out[r0 + (e * 2 + 1) * 16 + rl] = e10[reg];
        out[r1 + (e * 2 + 1) * 16 + rl] = e11[reg];
      }
    }
  }
}

extern "C" void kernel_launch(void* const* d_in, const int* in_sizes, int n_in,
                              void* d_out, int out_size, void* d_ws, size_t ws_size,
                              hipStream_t stream) {
  const float* nh = (const float*)d_in[0];
  const float* te = (const float*)d_in[1];
  const float* U  = (const float*)d_in[2];
  const float* bw = (const float*)d_in[3];
  const float* Ut = (const float*)d_in[4];
  const float* bt = (const float*)d_in[5];
  const float* T  = (const float*)d_in[6];
  const float* UO = (const float*)d_in[7];
  const float* bO = (const float*)d_in[8];
  float* out = (float*)d_out;

  unsigned* ws32 = (unsigned*)d_ws;
  hipLaunchKernelGGL(hosvd_prep, dim3(488), dim3(256), 0, stream, U, T, UO, ws32);

  const u16* BTf  = (const u16*)d_ws;         // 184320 u16
  const u16* UcTf = BTf + 184320;             // 32768 u16
  const u16* UOTf = UcTf + 32768;             // 32768 u16

  const int bs = in_sizes[0] / 512;           // (BS,2,256)
  hipLaunchKernelGGL(hosvd_main, dim3(bs / TB), dim3(NTHR), 0, stream,
                     nh, te, bw, Ut, bt, bO, BTf, UcTf, UOTf, out);
}

// Round 9
// 41.490 us; speedup vs baseline: 1.0684x; 1.0684x over previous
//
#include <hip/hip_runtime.h>

#define NTHR 512
#define TB 32

typedef __attribute__((ext_vector_type(8))) short bf16x8;
typedef __attribute__((ext_vector_type(4))) float f32x4;
typedef float4 f4;
typedef unsigned short u16;

__device__ __forceinline__ u16 f2b(float x) {
  union { float f; unsigned u; } v; v.f = x;
  unsigned r = (v.u + 0x7fffu + ((v.u >> 16) & 1u)) >> 16;
  return (u16)r;
}
__device__ __forceinline__ float b2f(u16 u) {
  union { unsigned u; float f; } v; v.u = ((unsigned)u) << 16;
  return v.f;
}
__device__ __forceinline__ unsigned pack2(float a, float b) {
  return (unsigned)f2b(a) | ((unsigned)f2b(b) << 16);
}
__device__ __forceinline__ unsigned cvtpk(float lo, float hi) {
  unsigned r;
  asm("v_cvt_pk_bf16_f32 %0, %1, %2" : "=v"(r) : "v"(lo), "v"(hi));
  return r;
}

// ---------------- prep: MFMA-fragment-ordered bf16 weights in ws ----------------
// BTf : frag_id = (a*10+kt)*9+p ; lane l, 8 k's: k' = kt*32+(l>>4)*8+j, col s=l&15
//       k' = q*18+r; k'>=306 or r==17 -> 0.
// UcTf: frag_id = (c*4+a)*8+kt;  k = kt*32+(l>>4)*8+j, col r = l&15.
// UOTf: frag_id = a*16+ht;       k = (l>>4)*8+j (k>=16 -> 0), col h = ht*16+(l&15).
extern "C" __global__ void hosvd_prep(const float* __restrict__ U,
                                      const float* __restrict__ T,
                                      const float* __restrict__ UO,
                                      unsigned* __restrict__ ws32) {
  int id = blockIdx.x * 256 + threadIdx.x;
  if (id < 92160) {                       // BTf: 23040 frags * 4 u32
    int j2 = id & 3, frag = id >> 2;
    int l = frag & 63, f2 = frag >> 6;    // f2 = (a*10+kt)*9+p
    int p = f2 % 9, akt = f2 / 9;
    int kt = akt % 10, a = akt / 10;
    int s = l & 15;
    float v[2];
    #pragma unroll
    for (int j = 0; j < 2; ++j) {
      int kp = kt * 32 + (l >> 4) * 8 + j2 * 2 + j;
      float x = 0.f;
      if (kp < 306) {
        int q = (unsigned)kp / 18u, r = kp - q * 18;
        if (r < 17) x = T[(((a * 9 + p) * 17 + q) * 17 + r) * 16 + s];
      }
      v[j] = x;
    }
    ws32[id] = pack2(v[0], v[1]);
  } else if (id < 108544) {               // UcTf: 4096 frags * 4 u32
    int rel = id - 92160;
    int j2 = rel & 3, frag = rel >> 2;
    int l = frag & 63, f2 = frag >> 6;
    int kt = f2 & 7, g = f2 >> 3;
    int a = g & 3, c = g >> 2;
    int rr = l & 15;
    int k = kt * 32 + (l >> 4) * 8 + j2 * 2;
    float v0 = U[((c * 4 + a) * 256 + k + 0) * 16 + rr];
    float v1 = U[((c * 4 + a) * 256 + k + 1) * 16 + rr];
    ws32[id] = pack2(v0, v1);
  } else if (id < 124928) {               // UOTf: 4096 frags * 4 u32
    int rel = id - 108544;
    int j2 = rel & 3, frag = rel >> 2;
    int l = frag & 63, f2 = frag >> 6;
    int ht = f2 & 15, a = f2 >> 4;
    int h = ht * 16 + (l & 15);
    int k = (l >> 4) * 8 + j2 * 2;
    float v0 = (k + 0 < 16) ? UO[(a * 16 + k + 0) * 256 + h] : 0.f;
    float v1 = (k + 1 < 16) ? UO[(a * 16 + k + 1) * 256 + h] : 0.f;
    ws32[id] = pack2(v0, v1);
  }
}

#define MFMA_B(A, B, C) __builtin_amdgcn_mfma_f32_16x16x32_bf16(A, B, C, 0, 0, 0)

// ---------------- main fused kernel ----------------
// 3-barrier skeleton. LDS (61184 B -> 2 blocks/CU):
//  s_u   [18688] u16: nh [32][520] + Ut f32[1024] tail (staging, phases B/C only)
//  s_ch  [32][164] u16: h[row][c*80+a*20+idx]; idx16=1.0, idx17..19=0 sentinels
//  s_tpt [36][32] f32: tp transposed [a*9+p][row]; p=8 row = 1.0 sentinel
//  s_g   [32][136] u16: [row][a*32+s], slots 16..31 zero; te f32[1056] alias early
extern "C" __global__ __launch_bounds__(NTHR, 4)
void hosvd_main(const float* __restrict__ nh, const float* __restrict__ te,
                const float* __restrict__ bw, const float* __restrict__ Ut,
                const float* __restrict__ bt, const float* __restrict__ bO,
                const u16* __restrict__ BTf, const u16* __restrict__ UcTf,
                const u16* __restrict__ UOTf, float* __restrict__ out) {
  __shared__ __align__(16) u16   s_u[18688];
  __shared__ __align__(16) u16   s_ch[TB * 164];
  __shared__ __align__(16) float s_tpt[36 * 32];
  __shared__ __align__(16) u16   s_g[TB * 136];

  const int t = threadIdx.x;
  const int ib0 = blockIdx.x * TB;
  const int w = t >> 6, l = t & 63;
  const int rl = l & 15, q = l >> 4;

  float* teL = (float*)s_g;             // te stage alias (dead before s_g writes)
  float* UtL = (float*)&s_u[16640];     // Ut stage in s_u tail

  //---- sentinels: slots 16..19 per (row,c,a): {1.0, 0, 0, 0} ----
  if (t < 256) {
    const int row = t >> 3, cc = (t >> 2) & 1, aa = t & 3;
    *(uint2*)&s_ch[row * 164 + cc * 80 + aa * 20 + 16] = make_uint2(0x3F80u, 0u);
  }
  if (t < 128) {  // s_tpt p=8 row = 1.0
    const int aa = t >> 5, row = t & 31;
    s_tpt[(aa * 9 + 8) * 32 + row] = 1.0f;
  }

  //---- stage: te -> teL, Ut -> UtL, nh -> s_u bf16 [32][520] ----
  if (t < 256) {
    const int row = t >> 3, k4 = t & 7;
    f4 v = *(const f4*)&te[(size_t)(ib0 + row) * 32 + k4 * 4];
    float* d = &teL[row * 33 + k4 * 4];
    d[0] = v.x; d[1] = v.y; d[2] = v.z; d[3] = v.w;
  } else {
    const int j = t - 256;                         // 256 f4 = 1024 floats of Ut
    *(f4*)&UtL[j * 4] = *(const f4*)&Ut[j * 4];
  }
  for (int lp = t; lp < 4096; lp += NTHR) {
    const int row = lp >> 7, rem = lp & 127;
    const int c = rem >> 6, k0 = (rem & 63) * 4;
    f4 v = *(const f4*)&nh[((size_t)(ib0 + row) * 2 + c) * 256 + k0];
    *(uint2*)&s_u[row * 520 + c * 256 + k0] =
        make_uint2(cvtpk(v.x, v.y), cvtpk(v.z, v.w));
  }
  __syncthreads();   // barrier 1

  //---- Phase B: tp = te @ Ut + bt -> s_tpt (transposed, f32) ----
  {
    const int i = t >> 4, o = t & 15;
    const int off = o * 2;
    const int aa = off >> 3, p0 = off & 7;
    float acc0 = bt[off], acc1 = bt[off + 1];
    #pragma unroll
    for (int k = 0; k < 32; ++k) {
      float tv = teL[i * 33 + k];
      float2 u = *(const float2*)&UtL[k * 32 + off];
      acc0 = fmaf(tv, u.x, acc0);
      acc1 = fmaf(tv, u.y, acc1);
    }
    s_tpt[(aa * 9 + p0) * 32 + i]     = acc0;
    s_tpt[(aa * 9 + p0 + 1) * 32 + i] = acc1;
  }

  //---- Phase C: ch = nh @ U + bw -> s_ch. Wave (c, a): both m tiles ----
  {
    const int c = w >> 2, a = w & 3;
    const u16* u0 = &UcTf[((size_t)((c * 4 + a) * 8) * 64 + l) * 8];
    bf16x8 C0 = *(const bf16x8*)(u0 + 0 * 512);
    bf16x8 C1 = *(const bf16x8*)(u0 + 1 * 512);
    bf16x8 C2 = *(const bf16x8*)(u0 + 2 * 512);
    bf16x8 C3 = *(const bf16x8*)(u0 + 3 * 512);
    bf16x8 C4 = *(const bf16x8*)(u0 + 4 * 512);
    bf16x8 C5 = *(const bf16x8*)(u0 + 5 * 512);
    bf16x8 C6 = *(const bf16x8*)(u0 + 6 * 512);
    bf16x8 C7 = *(const bf16x8*)(u0 + 7 * 512);
    f32x4 ac0 = {0.f, 0.f, 0.f, 0.f}, ac1 = {0.f, 0.f, 0.f, 0.f};
    #define PCKT(KT, CB)                                                          \
    {                                                                             \
      bf16x8 A0_ = *(const bf16x8*)&s_u[rl * 520 + c * 256 + KT * 32 + 8 * q];    \
      bf16x8 A1_ = *(const bf16x8*)&s_u[(16 + rl) * 520 + c * 256 + KT * 32 + 8 * q]; \
      ac0 = MFMA_B(A0_, CB, ac0);                                                 \
      ac1 = MFMA_B(A1_, CB, ac1);                                                 \
    }
    PCKT(0, C0) PCKT(1, C1) PCKT(2, C2) PCKT(3, C3)
    PCKT(4, C4) PCKT(5, C5) PCKT(6, C6) PCKT(7, C7)
    #undef PCKT
    const float bias = bw[(c * 4 + a) * 16 + rl];
    #pragma unroll
    for (int reg = 0; reg < 4; ++reg) {
      s_ch[(4 * q + reg) * 164 + c * 80 + a * 20 + rl]      = f2b(ac0[reg] + bias);
      s_ch[(16 + 4 * q + reg) * 164 + c * 80 + a * 20 + rl] = f2b(ac1[reg] + bias);
    }
  }
  __syncthreads();   // barrier 2: s_ch + s_tpt ready; teL alias dead

  //---- Core: wave (a, m) runs FULL K, barrier-free. A built from s_ch. ----
  {
    const int a = w & 3, m = w >> 2;
    const int row = m * 16 + rl;
    const u16* h1g = &s_ch[row * 164 + a * 20];        // h1 group (+18/19 zeroed)
    const u16* h2g = &s_ch[row * 164 + 80 + a * 20];   // h2 group

    f32x4 acc[9];
    #pragma unroll
    for (int p = 0; p < 9; ++p) acc[p] = (f32x4){0.f, 0.f, 0.f, 0.f};

    __builtin_amdgcn_s_setprio(1);
    #pragma unroll
    for (int kt = 0; kt < 10; ++kt) {
      // 9 B frags for this kt (issued first — latency hides under A-build)
      const u16* bp = &BTf[(size_t)((a * 10 + kt) * 9) * 512 + l * 8];
      bf16x8 B0 = *(const bf16x8*)(bp + 0 * 512);
      bf16x8 B1 = *(const bf16x8*)(bp + 1 * 512);
      bf16x8 B2 = *(const bf16x8*)(bp + 2 * 512);
      bf16x8 B3 = *(const bf16x8*)(bp + 3 * 512);
      bf16x8 B4 = *(const bf16x8*)(bp + 4 * 512);
      bf16x8 B5 = *(const bf16x8*)(bp + 5 * 512);
      bf16x8 B6 = *(const bf16x8*)(bp + 6 * 512);
      bf16x8 B7 = *(const bf16x8*)(bp + 7 * 512);
      bf16x8 B8 = *(const bf16x8*)(bp + 8 * 512);

      // A frag in-register: O[row][k'] = h1[qq]*h2[rr], k' = kt*32+8q+j
      const int k0 = kt * 32 + 8 * q;
      const unsigned qq0 = (unsigned)k0 / 18u;
      const int rr0 = k0 - (int)qq0 * 18;
      const int brk = 18 - rr0;
      const float h1a = b2f(h1g[qq0]);
      const float h1b = b2f(h1g[qq0 + 1]);   // slot<=19, zero-init'd
      float hv[8];
      #pragma unroll
      for (int j = 0; j < 8; ++j) {
        int rr = rr0 + j;
        rr = (rr >= 18) ? rr - 18 : rr;
        const float h2v = b2f(h2g[rr]);
        const float h1v = (j < brk) ? h1a : h1b;
        hv[j] = h1v * h2v;
      }
      union { unsigned u[4]; bf16x8 v; } Au;
      Au.u[0] = cvtpk(hv[0], hv[1]);
      Au.u[1] = cvtpk(hv[2], hv[3]);
      Au.u[2] = cvtpk(hv[4], hv[5]);
      Au.u[3] = cvtpk(hv[6], hv[7]);

      acc[0] = MFMA_B(Au.v, B0, acc[0]);
      acc[1] = MFMA_B(Au.v, B1, acc[1]);
      acc[2] = MFMA_B(Au.v, B2, acc[2]);
      acc[3] = MFMA_B(Au.v, B3, acc[3]);
      acc[4] = MFMA_B(Au.v, B4, acc[4]);
      acc[5] = MFMA_B(Au.v, B5, acc[5]);
      acc[6] = MFMA_B(Au.v, B6, acc[6]);
      acc[7] = MFMA_B(Au.v, B7, acc[7]);
      acc[8] = MFMA_B(Au.v, B8, acc[8]);
    }
    __builtin_amdgcn_s_setprio(0);

    //-- h0-weighted fold + direct s_g write (no reduce) --
    float gp[4] = {0.f, 0.f, 0.f, 0.f};
    #pragma unroll
    for (int p = 0; p < 9; ++p) {
      f4 tv = *(const f4*)&s_tpt[(a * 9 + p) * 32 + m * 16 + 4 * q];
      gp[0] = fmaf(tv.x, acc[p][0], gp[0]);
      gp[1] = fmaf(tv.y, acc[p][1], gp[1]);
      gp[2] = fmaf(tv.z, acc[p][2], gp[2]);
      gp[3] = fmaf(tv.w, acc[p][3], gp[3]);
    }
    #pragma unroll
    for (int reg = 0; reg < 4; ++reg) {
      const int row2 = m * 16 + 4 * q + reg;
      s_g[row2 * 136 + a * 32 + rl]      = f2b(gp[reg]);
      s_g[row2 * 136 + a * 32 + 16 + rl] = 0;   // zero K-pad for phase E
    }
  }
  __syncthreads();   // barrier 3: s_g ready

  //---- Phase E: out = g @ U_output + b_output. Wave e: ht {2e,2e+1}, both m ----
  {
    const int e = w;
    #pragma unroll
    for (int a = 0; a < 4; ++a) {
      const u16* ub = &UOTf[((size_t)(a * 16 + e * 2) * 64 + l) * 8];
      bf16x8 E0 = *(const bf16x8*)(ub);
      bf16x8 E1 = *(const bf16x8*)(ub + 512);
      bf16x8 A0 = *(const bf16x8*)&s_g[rl * 136 + a * 32 + 8 * q];
      bf16x8 A1 = *(const bf16x8*)&s_g[(16 + rl) * 136 + a * 32 + 8 * q];
      const float b0 = bO[a * 256 + (e * 2 + 0) * 16 + rl];
      const float b1 = bO[a * 256 + (e * 2 + 1) * 16 + rl];
      f32x4 e00 = {b0, b0, b0, b0}, e01 = e00;
      f32x4 e10 = {b1, b1, b1, b1}, e11 = e10;
      e00 = MFMA_B(A0, E0, e00);
      e01 = MFMA_B(A1, E0, e01);
      e10 = MFMA_B(A0, E1, e10);
      e11 = MFMA_B(A1, E1, e11);
      #pragma unroll
      for (int reg = 0; reg < 4; ++reg) {
        const size_t r0 = (size_t)(ib0 + 4 * q + reg) * 1024 + a * 256;
        const size_t r1 = (size_t)(ib0 + 16 + 4 * q + reg) * 1024 + a * 256;
        out[r0 + (e * 2 + 0) * 16 + rl] = e00[reg];
        out[r1 + (e * 2 + 0) * 16 + rl] = e01[reg];
        out[r0 + (e * 2 + 1) * 16 + rl] = e10[reg];
        out[r1 + (e * 2 + 1) * 16 + rl] = e11[reg];
      }
    }
  }
}

extern "C" void kernel_launch(void* const* d_in, const int* in_sizes, int n_in,
                              void* d_out, int out_size, void* d_ws, size_t ws_size,
                              hipStream_t stream) {
  const float* nh = (const float*)d_in[0];
  const float* te = (const float*)d_in[1];
  const float* U  = (const float*)d_in[2];
  const float* bw = (const float*)d_in[3];
  const float* Ut = (const float*)d_in[4];
  const float* bt = (const float*)d_in[5];
  const float* T  = (const float*)d_in[6];
  const float* UO = (const float*)d_in[7];
  const float* bO = (const float*)d_in[8];
  float* out = (float*)d_out;

  unsigned* ws32 = (unsigned*)d_ws;
  hipLaunchKernelGGL(hosvd_prep, dim3(488), dim3(256), 0, stream, U, T, UO, ws32);

  const u16* BTf  = (const u16*)d_ws;         // 184320 u16
  const u16* UcTf = BTf + 184320;             // 32768 u16
  const u16* UOTf = UcTf + 32768;             // 32768 u16

  const int bs = in_sizes[0] / 512;           // (BS,2,256)
  hipLaunchKernelGGL(hosvd_main, dim3(bs / TB), dim3(NTHR), 0, stream,
                     nh, te, bw, Ut, bt, bO, BTf, UcTf, UOTf, out);
}

// Round 10
// 39.474 us; speedup vs baseline: 1.1229x; 1.0511x over previous
//
#include <hip/hip_runtime.h>

#define NTHR 512
#define TB 32

typedef __attribute__((ext_vector_type(8))) short bf16x8;
typedef __attribute__((ext_vector_type(16))) float f32x16;
typedef float4 f4;
typedef unsigned short u16;

__device__ __forceinline__ u16 f2b(float x) {
  union { float f; unsigned u; } v; v.f = x;
  unsigned r = (v.u + 0x7fffu + ((v.u >> 16) & 1u)) >> 16;
  return (u16)r;
}
__device__ __forceinline__ float b2f(u16 u) {
  union { unsigned u; float f; } v; v.u = ((unsigned)u) << 16;
  return v.f;
}
__device__ __forceinline__ unsigned pack2(float a, float b) {
  return (unsigned)f2b(a) | ((unsigned)f2b(b) << 16);
}
__device__ __forceinline__ unsigned cvtpk(float lo, float hi) {
  unsigned r;
  asm("v_cvt_pk_bf16_f32 %0, %1, %2" : "=v"(r) : "v"(lo), "v"(hi));
  return r;
}

#define MFMA32(A, B, C) __builtin_amdgcn_mfma_f32_32x32x16_bf16(A, B, C, 0, 0, 0)

// ---------------- prep: 32x32x16-fragment-ordered bf16 weights ----------------
// All frags: lane l, col n = base + (l&31), k = kstep*16 + (l>>5)*8 + j (j=0..7).
// BTf : frag = (a*20+ks)*5+nt, n = nt*32+(l&31) -> (p=n>>4, s=n&15);
//       k' = ks*16+(l>>5)*8+j -> (q=k'/18, r=k'%18); zero if p>8 | q>16 | r>16.
// UcTf: frag = (c*16+ks)*2+nt, n -> (a=n>>4, r=n&15); k = ks*16+(l>>5)*8+j.
// UOTf: frag = a*8+ht, col h = ht*32+(l&31); k = (l>>5)*8+j (K=16 exact).
extern "C" __global__ void hosvd_prep(const float* __restrict__ U,
                                      const float* __restrict__ T,
                                      const float* __restrict__ UO,
                                      unsigned* __restrict__ ws32) {
  int id = blockIdx.x * 256 + threadIdx.x;
  if (id < 102400) {                      // BTf: 25600 frags * 4 u32
    int j2 = id & 3, frag = id >> 2;
    int l = frag & 63, f2 = frag >> 6;    // f2 = (a*20+ks)*5+nt
    int nt = f2 % 5, aks = f2 / 5;
    int ks = aks % 20, a = aks / 20;
    int n = nt * 32 + (l & 31);
    int p = n >> 4, s = n & 15;
    float v[2];
    #pragma unroll
    for (int j = 0; j < 2; ++j) {
      int kp = ks * 16 + (l >> 5) * 8 + j2 * 2 + j;
      int q = (unsigned)kp / 18u, r = kp - q * 18;
      float x = 0.f;
      if (p <= 8 && q <= 16 && r <= 16)
        x = T[(((a * 9 + p) * 17 + q) * 17 + r) * 16 + s];
      v[j] = x;
    }
    ws32[id] = pack2(v[0], v[1]);
  } else if (id < 118784) {               // UcTf: 4096 frags * 4 u32
    int rel = id - 102400;
    int j2 = rel & 3, frag = rel >> 2;
    int l = frag & 63, f2 = frag >> 6;    // f2 = (c*16+ks)*2+nt
    int nt = f2 & 1, ks = (f2 >> 1) & 15, c = f2 >> 5;
    int n = nt * 32 + (l & 31);
    int a = n >> 4, rr = n & 15;
    int k = ks * 16 + (l >> 5) * 8 + j2 * 2;
    float v0 = U[((c * 4 + a) * 256 + k + 0) * 16 + rr];
    float v1 = U[((c * 4 + a) * 256 + k + 1) * 16 + rr];
    ws32[id] = pack2(v0, v1);
  } else if (id < 126976) {               // UOTf: 2048 frags * 4 u32
    int rel = id - 118784;
    int j2 = rel & 3, frag = rel >> 2;
    int l = frag & 63, f2 = frag >> 6;    // f2 = a*8+ht
    int ht = f2 & 7, a = f2 >> 3;
    int h = ht * 32 + (l & 31);
    int k = (l >> 5) * 8 + j2 * 2;        // < 16 always
    float v0 = UO[(a * 16 + k + 0) * 256 + h];
    float v1 = UO[(a * 16 + k + 1) * 256 + h];
    ws32[id] = pack2(v0, v1);
  }
}

// ---------------- main fused kernel ----------------
// 3-barrier skeleton, 32x32x16 MFMA everywhere. LDS 56704 B (2 blocks/CU):
//  s_u   [20800] u16: nh [32][520] | Ut f32[1024] @16640 | te f32[1056] @18688
//        post-barrier-2 alias: s_red f32[2][4][32][16] (16 KB) at byte 0
//  s_ch  [32][164] u16: h[row][c*80+a*20+idx]; idx16=1.0, idx17..19=0 sentinels
//  s_tpt [36][32] f32: tp transposed [a*9+p][row]; p=8 row = 1.0 sentinel
extern "C" __global__ __launch_bounds__(NTHR, 4)
void hosvd_main(const float* __restrict__ nh, const float* __restrict__ te,
                const float* __restrict__ bw, const float* __restrict__ Ut,
                const float* __restrict__ bt, const float* __restrict__ bO,
                const u16* __restrict__ BTf, const u16* __restrict__ UcTf,
                const u16* __restrict__ UOTf, float* __restrict__ out) {
  __shared__ __align__(16) u16   s_u[20800];
  __shared__ __align__(16) u16   s_ch[TB * 164];
  __shared__ __align__(16) float s_tpt[36 * 32];

  const int t = threadIdx.x;
  const int ib0 = blockIdx.x * TB;
  const int w = t >> 6, l = t & 63;
  const int l31 = l & 31, hi = l >> 5;

  float* UtL = (float*)&s_u[16640];
  float* teL = (float*)&s_u[18688];
  float* s_redf = (float*)s_u;          // post-barrier-2 alias (16 KB)

  //---- sentinels ----
  if (t < 256) {  // s_ch idx 16..19 = {1.0, 0, 0, 0} per (row,c,a)
    const int row = t >> 3, cc = (t >> 2) & 1, aa = t & 3;
    *(uint2*)&s_ch[row * 164 + cc * 80 + aa * 20 + 16] = make_uint2(0x3F80u, 0u);
  }
  if (t < 128) {  // s_tpt p=8 row = 1.0
    const int aa = t >> 5, row = t & 31;
    s_tpt[(aa * 9 + 8) * 32 + row] = 1.0f;
  }

  //---- stage: te -> teL, Ut -> UtL, nh -> s_u bf16 [32][520] ----
  if (t < 256) {
    const int row = t >> 3, k4 = t & 7;
    f4 v = *(const f4*)&te[(size_t)(ib0 + row) * 32 + k4 * 4];
    float* d = &teL[row * 33 + k4 * 4];
    d[0] = v.x; d[1] = v.y; d[2] = v.z; d[3] = v.w;
  } else {
    const int j = t - 256;
    *(f4*)&UtL[j * 4] = *(const f4*)&Ut[j * 4];
  }
  for (int lp = t; lp < 4096; lp += NTHR) {
    const int row = lp >> 7, rem = lp & 127;
    const int c = rem >> 6, k0 = (rem & 63) * 4;
    f4 v = *(const f4*)&nh[((size_t)(ib0 + row) * 2 + c) * 256 + k0];
    *(uint2*)&s_u[row * 520 + c * 256 + k0] =
        make_uint2(cvtpk(v.x, v.y), cvtpk(v.z, v.w));
  }
  __syncthreads();   // barrier 1

  //---- Phase C (waves 0-3) || Phase B (waves 4-7) ----
  if (w < 4) {
    const int c = w & 1, nt2 = w >> 1;
    f32x16 accC = {0.f, 0.f, 0.f, 0.f, 0.f, 0.f, 0.f, 0.f,
                   0.f, 0.f, 0.f, 0.f, 0.f, 0.f, 0.f, 0.f};
    #pragma unroll
    for (int ks = 0; ks < 16; ++ks) {
      bf16x8 Av = *(const bf16x8*)&s_u[l31 * 520 + c * 256 + ks * 16 + hi * 8];
      bf16x8 Bv = *(const bf16x8*)
          &UcTf[(size_t)(((c * 16 + ks) * 2 + nt2) * 64 + l) * 8];
      accC = MFMA32(Av, Bv, accC);
    }
    const int n = nt2 * 32 + l31;
    const int ca = n >> 4, rr = n & 15;
    const float bias = bw[(c * 4 + ca) * 16 + rr];
    #pragma unroll
    for (int reg = 0; reg < 16; ++reg) {
      const int row = (reg & 3) + 8 * (reg >> 2) + 4 * hi;
      s_ch[row * 164 + c * 80 + ca * 20 + rr] = f2b(accC[reg] + bias);
    }
  } else {
    const int t2 = t - 256;
    const int i = t2 >> 3, off = (t2 & 7) * 4;
    float ac0 = bt[off], ac1 = bt[off + 1], ac2 = bt[off + 2], ac3 = bt[off + 3];
    #pragma unroll
    for (int k = 0; k < 32; ++k) {
      const float tv = teL[i * 33 + k];
      f4 u = *(const f4*)&UtL[k * 32 + off];
      ac0 = fmaf(tv, u.x, ac0);
      ac1 = fmaf(tv, u.y, ac1);
      ac2 = fmaf(tv, u.z, ac2);
      ac3 = fmaf(tv, u.w, ac3);
    }
    #pragma unroll
    for (int jj = 0; jj < 4; ++jj) {
      const int o2 = off + jj;
      const float v = (jj == 0) ? ac0 : (jj == 1) ? ac1 : (jj == 2) ? ac2 : ac3;
      s_tpt[((o2 >> 3) * 9 + (o2 & 7)) * 32 + i] = v;
    }
  }
  __syncthreads();   // barrier 2: s_ch + s_tpt ready; s_u nh region dead

  //---- Core: wave (a, kh) — 10 ksteps, M=32, N=160(5 tiles), in-reg A ----
  {
    const int a = w & 3, kh = w >> 2;
    const u16* h1g = &s_ch[l31 * 164 + a * 20];
    const u16* h2g = h1g + 80;

    f32x16 acc[5];
    #pragma unroll
    for (int nt = 0; nt < 5; ++nt)
      acc[nt] = (f32x16){0.f, 0.f, 0.f, 0.f, 0.f, 0.f, 0.f, 0.f,
                         0.f, 0.f, 0.f, 0.f, 0.f, 0.f, 0.f, 0.f};

    __builtin_amdgcn_s_setprio(1);
    #pragma unroll
    for (int ks2 = 0; ks2 < 10; ++ks2) {
      const int ks = kh * 10 + ks2;
      const u16* bp = &BTf[(size_t)((a * 20 + ks) * 5) * 512 + l * 8];
      bf16x8 B0 = *(const bf16x8*)(bp + 0 * 512);
      bf16x8 B1 = *(const bf16x8*)(bp + 1 * 512);
      bf16x8 B2 = *(const bf16x8*)(bp + 2 * 512);
      bf16x8 B3 = *(const bf16x8*)(bp + 3 * 512);
      bf16x8 B4 = *(const bf16x8*)(bp + 4 * 512);

      // A frag: O[row=l31][k'], k' = ks*16 + hi*8 + j
      const int k0 = ks * 16 + hi * 8;
      const unsigned q0 = (unsigned)k0 / 18u;
      const int r0 = k0 - (int)q0 * 18;
      const int brk = 18 - r0;
      const float h1a = b2f(h1g[q0]);
      const float h1b = b2f(h1g[q0 + 1]);   // slots <=19 zero-init'd
      float hv[8];
      #pragma unroll
      for (int j = 0; j < 8; ++j) {
        int rr = r0 + j;
        rr = (rr >= 18) ? rr - 18 : rr;
        const float h2v = b2f(h2g[rr]);
        hv[j] = ((j < brk) ? h1a : h1b) * h2v;
      }
      union { unsigned u[4]; bf16x8 v; } Au;
      Au.u[0] = cvtpk(hv[0], hv[1]);
      Au.u[1] = cvtpk(hv[2], hv[3]);
      Au.u[2] = cvtpk(hv[4], hv[5]);
      Au.u[3] = cvtpk(hv[6], hv[7]);

      acc[0] = MFMA32(Au.v, B0, acc[0]);
      acc[1] = MFMA32(Au.v, B1, acc[1]);
      acc[2] = MFMA32(Au.v, B2, acc[2]);
      acc[3] = MFMA32(Au.v, B3, acc[3]);
      acc[4] = MFMA32(Au.v, B4, acc[4]);
    }
    __builtin_amdgcn_s_setprio(0);

    //-- per-lane h0 fold (col -> p), then parity combine via shfl_xor(16) --
    float gp[16];
    #pragma unroll
    for (int reg = 0; reg < 16; ++reg) gp[reg] = 0.f;
    #pragma unroll
    for (int nt = 0; nt < 5; ++nt) {
      int pp = nt * 2 + (l31 >> 4);
      if (pp > 8) pp = 8;                  // p=9 pad: acc cols are zero
      const float* tpb = &s_tpt[(a * 9 + pp) * 32 + 4 * hi];
      f4 t0 = *(const f4*)&tpb[0];
      f4 t1 = *(const f4*)&tpb[8];
      f4 t2 = *(const f4*)&tpb[16];
      f4 t3 = *(const f4*)&tpb[24];
      gp[0]  = fmaf(t0.x, acc[nt][0],  gp[0]);
      gp[1]  = fmaf(t0.y, acc[nt][1],  gp[1]);
      gp[2]  = fmaf(t0.z, acc[nt][2],  gp[2]);
      gp[3]  = fmaf(t0.w, acc[nt][3],  gp[3]);
      gp[4]  = fmaf(t1.x, acc[nt][4],  gp[4]);
      gp[5]  = fmaf(t1.y, acc[nt][5],  gp[5]);
      gp[6]  = fmaf(t1.z, acc[nt][6],  gp[6]);
      gp[7]  = fmaf(t1.w, acc[nt][7],  gp[7]);
      gp[8]  = fmaf(t2.x, acc[nt][8],  gp[8]);
      gp[9]  = fmaf(t2.y, acc[nt][9],  gp[9]);
      gp[10] = fmaf(t2.z, acc[nt][10], gp[10]);
      gp[11] = fmaf(t2.w, acc[nt][11], gp[11]);
      gp[12] = fmaf(t3.x, acc[nt][12], gp[12]);
      gp[13] = fmaf(t3.y, acc[nt][13], gp[13]);
      gp[14] = fmaf(t3.z, acc[nt][14], gp[14]);
      gp[15] = fmaf(t3.w, acc[nt][15], gp[15]);
    }
    #pragma unroll
    for (int reg = 0; reg < 16; ++reg)
      gp[reg] += __shfl_xor(gp[reg], 16, 64);
    if ((l & 16) == 0) {
      const int s = l & 15;
      #pragma unroll
      for (int reg = 0; reg < 16; ++reg) {
        const int row = (reg & 3) + 8 * (reg >> 2) + 4 * hi;
        s_redf[((kh * 4 + a) * 32 + row) * 16 + s] = gp[reg];
      }
    }
  }
  __syncthreads();   // barrier 3: s_red ready

  //---- Phase E: wave = ht (32 cols), K=16 exact; K-reduce fused in A-build ----
  {
    #pragma unroll
    for (int a = 0; a < 4; ++a) {
      const float* r0p = &s_redf[((0 + a) * 32 + l31) * 16 + hi * 8];
      const float* r1p = &s_redf[((4 + a) * 32 + l31) * 16 + hi * 8];
      f4 xa = *(const f4*)&r0p[0], xb = *(const f4*)&r0p[4];
      f4 ya = *(const f4*)&r1p[0], yb = *(const f4*)&r1p[4];
      union { unsigned u[4]; bf16x8 v; } Au;
      Au.u[0] = cvtpk(xa.x + ya.x, xa.y + ya.y);
      Au.u[1] = cvtpk(xa.z + ya.z, xa.w + ya.w);
      Au.u[2] = cvtpk(xb.x + yb.x, xb.y + yb.y);
      Au.u[3] = cvtpk(xb.z + yb.z, xb.w + yb.w);
      bf16x8 Bv = *(const bf16x8*)&UOTf[((size_t)(a * 8 + w) * 64 + l) * 8];
      const int h = w * 32 + l31;
      const float bias = bO[a * 256 + h];
      f32x16 accE = {bias, bias, bias, bias, bias, bias, bias, bias,
                     bias, bias, bias, bias, bias, bias, bias, bias};
      accE = MFMA32(Au.v, Bv, accE);
      #pragma unroll
      for (int reg = 0; reg < 16; ++reg) {
        const int row = (reg & 3) + 8 * (reg >> 2) + 4 * hi;
        out[(size_t)(ib0 + row) * 1024 + a * 256 + h] = accE[reg];
      }
    }
  }
}

extern "C" void kernel_launch(void* const* d_in, const int* in_sizes, int n_in,
                              void* d_out, int out_size, void* d_ws, size_t ws_size,
                              hipStream_t stream) {
  const float* nh = (const float*)d_in[0];
  const float* te = (const float*)d_in[1];
  const float* U  = (const float*)d_in[2];
  const float* bw = (const float*)d_in[3];
  const float* Ut = (const float*)d_in[4];
  const float* bt = (const float*)d_in[5];
  const float* T  = (const float*)d_in[6];
  const float* UO = (const float*)d_in[7];
  const float* bO = (const float*)d_in[8];
  float* out = (float*)d_out;

  unsigned* ws32 = (unsigned*)d_ws;
  hipLaunchKernelGGL(hosvd_prep, dim3(496), dim3(256), 0, stream, U, T, UO, ws32);

  const u16* BTf  = (const u16*)d_ws;         // 204800 u16
  const u16* UcTf = BTf + 204800;             // 32768 u16
  const u16* UOTf = UcTf + 32768;             // 16384 u16

  const int bs = in_sizes[0] / 512;           // (BS,2,256)
  hipLaunchKernelGGL(hosvd_main, dim3(bs / TB), dim3(NTHR), 0, stream,
                     nh, te, bw, Ut, bt, bO, BTf, UcTf, UOTf, out);
}